// Round 12
// baseline (116.262 us; speedup 1.0000x reference)
//
#include <hip/hip_runtime.h>
#include <math.h>

#define T_ 4096
#define D_ 128
#define NTOK 8192
#define CHUNK 64
#define NCB 64        // chunks per batch
#define NCH 128       // total chunks
#define LN_EPS 1e-5f
#define EPS_ATTN 1e-6f

typedef __attribute__((ext_vector_type(8))) short bf16x8;
typedef __attribute__((ext_vector_type(4))) short bf16x4;
typedef __attribute__((ext_vector_type(2))) short bf16x2;
typedef __attribute__((ext_vector_type(4))) float f32x4;

__device__ inline short f2bf(float f) {
  unsigned u = __builtin_bit_cast(unsigned, f);
  u += 0x7fffu + ((u >> 16) & 1u);
  return (short)(u >> 16);
}
__device__ inline float bf2f(short s) {
  unsigned u = ((unsigned)(unsigned short)s) << 16;
  return __builtin_bit_cast(float, u);
}
__device__ inline float phi_(float x) { return x > 0.f ? x + 1.f : __expf(x); }

// ============ K0: weight transpose (bid<5) || LN1 -> xb bf16 (bid>=5) ============
__global__ __launch_bounds__(256) void k_prep(const float* __restrict__ Wq,
    const float* __restrict__ Wk, const float* __restrict__ Wv,
    const float* __restrict__ Wg, const float* __restrict__ Wo,
    const float* __restrict__ tokens, const float* __restrict__ g1,
    const float* __restrict__ b1,
    short* __restrict__ WT, short* __restrict__ xb) {
  const int tid = threadIdx.x;
  if (blockIdx.x < 5) {
    const float* W = blockIdx.x==0?Wq: blockIdx.x==1?Wk: blockIdx.x==2?Wv: blockIdx.x==3?Wg:Wo;
    short* out = WT + blockIdx.x*D_*D_;
    __shared__ float lds[128][132];
    #pragma unroll
    for (int it = 0; it < 16; ++it) {
      const int f = it*1024 + tid*4;
      const int k = f >> 7, n = f & 127;
      const float4 v = *(const float4*)&W[f];
      lds[k][n] = v.x; lds[k][n+1] = v.y; lds[k][n+2] = v.z; lds[k][n+3] = v.w;
    }
    __syncthreads();
    #pragma unroll
    for (int it = 0; it < 16; ++it) {
      const int f = it*1024 + tid*4;
      const int n = f >> 7, k = f & 127;
      bf16x4 o;
      o.x = f2bf(lds[k][n]);   o.y = f2bf(lds[k+1][n]);
      o.z = f2bf(lds[k+2][n]); o.w = f2bf(lds[k+3][n]);
      *(bf16x4*)&out[f] = o;
    }
  } else {
    const int m0 = (blockIdx.x - 5) * 32;
    const int w = tid >> 6, l = tid & 63;
    const float2 gg = *(const float2*)&g1[l*2];
    const float2 bb = *(const float2*)&b1[l*2];
    float2 tv[8];
    #pragma unroll
    for (int it = 0; it < 8; ++it)
      tv[it] = *(const float2*)&tokens[(m0 + w*8 + it)*D_ + l*2];
    #pragma unroll
    for (int it = 0; it < 8; ++it) {
      const float2 v = tv[it];
      float s = v.x + v.y, qq = v.x*v.x + v.y*v.y;
      #pragma unroll
      for (int off = 1; off < 64; off <<= 1) {
        s += __shfl_xor(s, off); qq += __shfl_xor(qq, off);
      }
      const float mean = s*(1.f/D_);
      const float r2 = rsqrtf(qq*(1.f/D_) - mean*mean + LN_EPS);
      bf16x2 o;
      o.x = f2bf((v.x-mean)*r2*gg.x + bb.x);
      o.y = f2bf((v.y-mean)*r2*gg.y + bb.y);
      *(bf16x2*)&xb[(m0 + w*8 + it)*D_ + l*2] = o;
    }
  }
}

// ============ K1: QKVG GEMMs, 32-token tiles, xb bf16 input ============
// y=0: Qp=phi(x@Wq) ; y=1: Kp+KpT=phi(x@Wk) ; y=2: VgT=(x@Wv)*sigmoid(x@Wg+bg)
__global__ __launch_bounds__(256) void k_qkvg(const short* __restrict__ xb,
    const short* __restrict__ WT, const float* __restrict__ bg,
    short* __restrict__ Qp, short* __restrict__ Kp, short* __restrict__ KpT,
    short* __restrict__ VgT) {
  const int m0 = blockIdx.x * 32;
  const int y = blockIdx.y;
  const int tid = threadIdx.x;
  const int w = tid >> 6, l = tid & 63;
  __shared__ short xs[32][136];
  __shared__ short wsd[128][136];

  for (int u = tid; u < 512; u += 256) {
    const int t = u >> 4, c8 = (u & 15)*8;
    *(bf16x8*)&xs[t][c8] = *(const bf16x8*)&xb[(m0+t)*D_ + c8];
  }

  auto stageW = [&](const short* __restrict__ Wb) {
    for (int v = tid; v < 2048; v += 256) {
      const int n = v >> 4, c8 = (v & 15)*8;
      *(bf16x8*)&wsd[n][c8] = *(const bf16x8*)&Wb[n*D_ + c8];
    }
  };

  const int i = l & 15, q = l >> 4;
  auto gemm = [&](f32x4 (*acc)[2]) {
    #pragma unroll
    for (int kk = 0; kk < 4; ++kk) {
      bf16x8 a[2], bfr[2];
      #pragma unroll
      for (int mt = 0; mt < 2; ++mt) a[mt] = *(const bf16x8*)&xs[mt*16+i][kk*32+q*8];
      #pragma unroll
      for (int nt = 0; nt < 2; ++nt) bfr[nt] = *(const bf16x8*)&wsd[w*32+nt*16+i][kk*32+q*8];
      #pragma unroll
      for (int mt = 0; mt < 2; ++mt)
        #pragma unroll
        for (int nt = 0; nt < 2; ++nt)
          acc[mt][nt] = __builtin_amdgcn_mfma_f32_16x16x32_bf16(a[mt], bfr[nt], acc[mt][nt], 0, 0, 0);
    }
  };

  stageW(WT + (y == 2 ? 2 : y)*D_*D_);
  __syncthreads();
  f32x4 acc[2][2];
  #pragma unroll
  for (int mt = 0; mt < 2; ++mt)
    #pragma unroll
    for (int nt = 0; nt < 2; ++nt) acc[mt][nt] = (f32x4){0.f,0.f,0.f,0.f};
  gemm(acc);

  if (y == 0) {
    #pragma unroll
    for (int mt = 0; mt < 2; ++mt)
      #pragma unroll
      for (int nt = 0; nt < 2; ++nt) {
        const int h = w*32 + nt*16 + i;
        #pragma unroll
        for (int r = 0; r < 4; ++r)
          Qp[(m0 + mt*16 + 4*q + r)*D_ + h] = f2bf(phi_(acc[mt][nt][r]));
      }
  } else if (y == 1) {
    #pragma unroll
    for (int mt = 0; mt < 2; ++mt)
      #pragma unroll
      for (int nt = 0; nt < 2; ++nt) {
        const int h = w*32 + nt*16 + i;
        const int t0 = m0 + mt*16 + 4*q;
        bf16x4 o;
        #pragma unroll
        for (int r = 0; r < 4; ++r) {
          const short bv = f2bf(phi_(acc[mt][nt][r]));
          Kp[(t0+r)*D_ + h] = bv;
          o[r] = bv;
        }
        *(bf16x4*)&KpT[h*NTOK + t0] = o;
      }
  } else {
    __syncthreads();
    stageW(WT + 3*D_*D_);            // Wg^T
    __syncthreads();
    f32x4 accg[2][2];
    #pragma unroll
    for (int mt = 0; mt < 2; ++mt)
      #pragma unroll
      for (int nt = 0; nt < 2; ++nt) accg[mt][nt] = (f32x4){0.f,0.f,0.f,0.f};
    gemm(accg);
    #pragma unroll
    for (int mt = 0; mt < 2; ++mt)
      #pragma unroll
      for (int nt = 0; nt < 2; ++nt) {
        const int h = w*32 + nt*16 + i;
        const int t0 = m0 + mt*16 + 4*q;
        const float bgd = bg[h];
        bf16x4 o;
        #pragma unroll
        for (int r = 0; r < 4; ++r) {
          const float gv = 1.f/(1.f + __expf(-(accg[mt][nt][r] + bgd)));
          o[r] = f2bf(acc[mt][nt][r] * gv);
        }
        *(bf16x4*)&VgT[h*NTOK + t0] = o;
      }
  }
}

// ============ K2: per-chunk KV^T quarters + Ksum (verified R10) ============
__global__ __launch_bounds__(256) void k_chunkkv(const short* __restrict__ KpT,
    const short* __restrict__ VgT,
    float* __restrict__ KVT, float* __restrict__ Ksum) {
  const int c = blockIdx.x, hh = blockIdx.y, dh = blockIdx.z;
  const int tid = threadIdx.x;
  const int tb = c*CHUNK;
  __shared__ short vgl[64][72];
  __shared__ short kpl[64][72];
  __shared__ float ksp[64][5];
  for (int u = tid; u < 512; u += 256) {
    const int dd = u >> 3, c8 = (u & 7)*8;
    *(bf16x8*)&vgl[dd][c8] = *(const bf16x8*)&VgT[(dh*64+dd)*NTOK + tb + c8];
    *(bf16x8*)&kpl[dd][c8] = *(const bf16x8*)&KpT[(hh*64+dd)*NTOK + tb + c8];
  }
  __syncthreads();
  const int w = tid >> 6, l = tid & 63, i = l & 15, q = l >> 4;
  f32x4 acc[4];
  #pragma unroll
  for (int nt = 0; nt < 4; ++nt) acc[nt] = (f32x4){0.f,0.f,0.f,0.f};
  #pragma unroll
  for (int kk = 0; kk < 2; ++kk) {
    bf16x8 a = *(const bf16x8*)&vgl[w*16+i][kk*32+q*8];
    #pragma unroll
    for (int nt = 0; nt < 4; ++nt) {
      bf16x8 bb = *(const bf16x8*)&kpl[nt*16+i][kk*32+q*8];
      acc[nt] = __builtin_amdgcn_mfma_f32_16x16x32_bf16(a, bb, acc[nt], 0, 0, 0);
    }
  }
  float* KVc = KVT + (size_t)c*16384;
  #pragma unroll
  for (int nt = 0; nt < 4; ++nt)
    #pragma unroll
    for (int r = 0; r < 4; ++r) {
      const int d = dh*64 + w*16 + 4*q + r;
      const int h = hh*64 + nt*16 + i;
      KVc[d*D_ + h] = acc[nt][r];
    }
  if (dh == 0) {
    const int h = tid >> 2, part = tid & 3;
    float s = 0.f;
    #pragma unroll
    for (int t = 0; t < 16; ++t) s += bf2f(kpl[h][part*16 + t]);
    ksp[h][part] = s;
    __syncthreads();
    if (tid < 64)
      Ksum[c*D_ + hh*64 + tid] = ksp[tid][0]+ksp[tid][1]+ksp[tid][2]+ksp[tid][3];
  }
}

// ============ K3: exclusive chunk prefix (verified R4/R9) ============
__global__ __launch_bounds__(256) void k_prefix(const float* __restrict__ KVT,
    short* __restrict__ KVTb, float* __restrict__ Ksum) {
  const int tid = threadIdx.x;
  if (blockIdx.x < 128) {
    const int b = blockIdx.x >> 6;
    const int e = (blockIdx.x & 63)*256 + tid;
    const size_t base = (size_t)b*NCB*16384 + e;
    float run = 0.f;
    #pragma unroll 8
    for (int c = 0; c < NCB; ++c) {
      const float v = KVT[base + (size_t)c*16384];
      KVTb[base + (size_t)c*16384] = f2bf(run);
      run += v;
    }
  } else {
    const int b = tid >> 7, h = tid & 127;
    float run = 0.f;
    #pragma unroll 8
    for (int c = 0; c < NCB; ++c) {
      const int idx = (b*NCB + c)*128 + h;
      const float v = Ksum[idx];
      Ksum[idx] = run;
      run += v;
    }
  }
}

// ============ K4: scores + attnout fused (verified mega stage-4, R6-R8) ============
__global__ __launch_bounds__(256) void k_attnout(const short* __restrict__ Qp,
    const short* __restrict__ Kp, const short* __restrict__ VgT,
    const short* __restrict__ KVTb, const float* __restrict__ Ksum,
    short* __restrict__ attn) {
  const int c = blockIdx.x, dh = blockIdx.y, tid = threadIdx.x;
  const int tb = c*CHUNK;
  __shared__ short at[64][200], bt[64][200];
  __shared__ float ksl[128], rsl[64], dpart[64][4], denl[64];
  const int w = tid >> 6, l = tid & 63, i = l & 15, q = l >> 4;
  for (int v = tid; v < 1024; v += 256) {
    const int t = v >> 4, c8 = (v & 15)*8;
    *(bf16x8*)&at[t][64 + c8] = *(const bf16x8*)&Qp[(tb+t)*D_ + c8];
    *(bf16x8*)&bt[t][c8]      = *(const bf16x8*)&Kp[(tb+t)*D_ + c8];
  }
  if (tid < 128) ksl[tid] = Ksum[c*D_ + tid];
  __syncthreads();
  // ---- scores: A = mask(Qp Kp^T), rowsums ----
  {
    f32x4 acc[4];
    #pragma unroll
    for (int nt = 0; nt < 4; ++nt) acc[nt] = (f32x4){0.f,0.f,0.f,0.f};
    #pragma unroll
    for (int kk = 0; kk < 4; ++kk) {
      bf16x8 a = *(const bf16x8*)&at[w*16+i][64 + kk*32+q*8];
      for (int nt = 0; nt <= w; ++nt) {
        bf16x8 bb = *(const bf16x8*)&bt[nt*16+i][kk*32+q*8];
        acc[nt] = __builtin_amdgcn_mfma_f32_16x16x32_bf16(a, bb, acc[nt], 0, 0, 0);
      }
    }
    float rs[4] = {0.f,0.f,0.f,0.f};
    #pragma unroll
    for (int nt = 0; nt < 4; ++nt)
      #pragma unroll
      for (int r = 0; r < 4; ++r) {
        const int t = w*16 + 4*q + r;
        const int s = nt*16 + i;
        const float v = (nt <= w && s <= t) ? acc[nt][r] : 0.f;
        rs[r] += v;
        at[t][s] = f2bf(v);
      }
    #pragma unroll
    for (int r = 0; r < 4; ++r) {
      #pragma unroll
      for (int off = 1; off < 16; off <<= 1) rs[r] += __shfl_xor(rs[r], off);
    }
    if (i == 0) {
      #pragma unroll
      for (int r = 0; r < 4; ++r) rsl[w*16 + 4*q + r] = rs[r];
    }
  }
  // ---- denominator partials (Qp region of at) ----
  {
    const int t = tid >> 2, part = tid & 3;
    float dot = 0.f;
    #pragma unroll
    for (int h = 0; h < 32; ++h)
      dot += bf2f(at[t][64 + part*32 + h]) * ksl[part*32 + h];
    dpart[t][part] = dot;
  }
  __syncthreads();
  if (tid < 64)
    denl[tid] = fmaxf(rsl[tid] + dpart[tid][0]+dpart[tid][1]+dpart[tid][2]+dpart[tid][3], EPS_ATTN);
  // ---- restage bt: Vg (cols 0:64), KV_prev (cols 64:192) ----
  for (int v = tid; v < 512; v += 256) {
    const int dd = v >> 3, c8 = (v & 7)*8;
    *(bf16x8*)&bt[dd][c8] = *(const bf16x8*)&VgT[(dh*64+dd)*NTOK + tb + c8];
  }
  for (int v = tid; v < 1024; v += 256) {
    const int dd = v >> 4, c8 = (v & 15)*8;
    *(bf16x8*)&bt[dd][64 + c8] = *(const bf16x8*)&KVTb[(size_t)c*16384 + (dh*64+dd)*D_ + c8];
  }
  __syncthreads();
  f32x4 acc2[4];
  #pragma unroll
  for (int nt = 0; nt < 4; ++nt) acc2[nt] = (f32x4){0.f,0.f,0.f,0.f};
  #pragma unroll
  for (int kk = 0; kk < 6; ++kk) {
    bf16x8 a = *(const bf16x8*)&at[w*16+i][kk*32+q*8];
    #pragma unroll
    for (int nt = 0; nt < 4; ++nt) {
      bf16x8 bb = *(const bf16x8*)&bt[nt*16+i][kk*32+q*8];
      acc2[nt] = __builtin_amdgcn_mfma_f32_16x16x32_bf16(a, bb, acc2[nt], 0, 0, 0);
    }
  }
  #pragma unroll
  for (int r = 0; r < 4; ++r) {
    const int t = w*16 + 4*q + r;
    const float inv = 1.f / denl[t];
    #pragma unroll
    for (int nt = 0; nt < 4; ++nt)
      attn[(size_t)(tb+t)*D_ + dh*64 + nt*16 + i] = f2bf(acc2[nt][r] * inv);
  }
}

// ============ K5: out = LN2(tokens + 0.1*(attn@Wo)), 16-token tiles (verified R10) ============
__global__ __launch_bounds__(256) void k_outln2(const short* __restrict__ attn,
    const short* __restrict__ WoT, const float* __restrict__ tokens,
    const float* __restrict__ g2, const float* __restrict__ b2,
    float* __restrict__ out) {
  const int m0 = blockIdx.x*16, tid = threadIdx.x;
  __shared__ short al[16][136], wl[128][136];
  __shared__ float tl[16][132];
  __shared__ float suml[16][4], ssql[16][4];
  __shared__ float meanl[16], rstdl[16];
  __shared__ float gl[128], bl2[128];
  for (int u = tid; u < 256; u += 256) {
    const int t = u >> 4, c8 = (u & 15)*8;
    *(bf16x8*)&al[t][c8] = *(const bf16x8*)&attn[(m0+t)*D_ + c8];
  }
  #pragma unroll
  for (int u = tid; u < 2048; u += 256) {
    const int n = u >> 4, c8 = (u & 15)*8;
    *(bf16x8*)&wl[n][c8] = *(const bf16x8*)&WoT[n*D_ + c8];
  }
  #pragma unroll
  for (int u = tid; u < 512; u += 256) {
    const int t = u >> 5, c4 = (u & 31)*4;
    *(float4*)&tl[t][c4] = *(const float4*)&tokens[(m0+t)*D_ + c4];
  }
  if (tid < 128) { gl[tid] = g2[tid]; bl2[tid] = b2[tid]; }
  __syncthreads();
  const int w = tid >> 6, l = tid & 63, i = l & 15, q = l >> 4;
  f32x4 acc[2];
  #pragma unroll
  for (int j = 0; j < 2; ++j) acc[j] = (f32x4){0.f,0.f,0.f,0.f};
  #pragma unroll
  for (int kk = 0; kk < 4; ++kk) {
    bf16x8 a = *(const bf16x8*)&al[i][kk*32+q*8];
    #pragma unroll
    for (int j = 0; j < 2; ++j) {
      bf16x8 bb = *(const bf16x8*)&wl[(w*2+j)*16+i][kk*32+q*8];
      acc[j] = __builtin_amdgcn_mfma_f32_16x16x32_bf16(a, bb, acc[j], 0, 0, 0);
    }
  }
  float p[4][2], ps[4], qs[4];
  #pragma unroll
  for (int r = 0; r < 4; ++r) {
    const int t = 4*q + r;
    ps[r] = 0.f; qs[r] = 0.f;
    #pragma unroll
    for (int j = 0; j < 2; ++j) {
      const int col = w*32 + j*16 + i;
      const float v = tl[t][col] + 0.1f*acc[j][r];
      p[r][j] = v; ps[r] += v; qs[r] += v*v;
    }
  }
  #pragma unroll
  for (int r = 0; r < 4; ++r) {
    #pragma unroll
    for (int off = 1; off < 16; off <<= 1) {
      ps[r] += __shfl_xor(ps[r], off);
      qs[r] += __shfl_xor(qs[r], off);
    }
  }
  if (i == 0) {
    #pragma unroll
    for (int r = 0; r < 4; ++r) {
      suml[4*q+r][w] = ps[r];
      ssql[4*q+r][w] = qs[r];
    }
  }
  __syncthreads();
  if (tid < 16) {
    const float s = suml[tid][0]+suml[tid][1]+suml[tid][2]+suml[tid][3];
    const float qq = ssql[tid][0]+ssql[tid][1]+ssql[tid][2]+ssql[tid][3];
    const float mean = s*(1.f/D_);
    meanl[tid] = mean;
    rstdl[tid] = rsqrtf(qq*(1.f/D_) - mean*mean + LN_EPS);
  }
  __syncthreads();
  #pragma unroll
  for (int r = 0; r < 4; ++r) {
    const int t = 4*q + r;
    const float mean = meanl[t], rr = rstdl[t];
    #pragma unroll
    for (int j = 0; j < 2; ++j) {
      const int col = w*32 + j*16 + i;
      out[(m0+t)*D_ + col] = (p[r][j]-mean)*rr*gl[col] + bl2[col];
    }
  }
}

extern "C" void kernel_launch(void* const* d_in, const int* in_sizes, int n_in,
                              void* d_out, int out_size, void* d_ws, size_t ws_size,
                              hipStream_t stream) {
  const float* tokens = (const float*)d_in[0];
  const float* Wq = (const float*)d_in[1];
  const float* Wk = (const float*)d_in[2];
  const float* Wv = (const float*)d_in[3];
  const float* Wg = (const float*)d_in[4];
  const float* bg = (const float*)d_in[5];
  const float* Wo = (const float*)d_in[6];
  const float* g1 = (const float*)d_in[7];
  const float* b1 = (const float*)d_in[8];
  const float* g2 = (const float*)d_in[9];
  const float* b2 = (const float*)d_in[10];

  // Layout (non-overlapping; R11's bug was WT/Ksum inside KVTb's 12-16MB range):
  char* base = (char*)d_ws;
  short* xb     = (short*)(base);                        // 0  .. 2MB
  short* Qp     = (short*)(base + (2u<<20));             // 2  .. 4MB
  short* Kp     = (short*)(base + (4u<<20));             // 4  .. 6MB
  short* KpT    = (short*)(base + (6u<<20));             // 6  .. 8MB
  short* VgT    = (short*)(base + (8u<<20));             // 8  ..10MB
  short* attn   = (short*)(base + (10u<<20));            // 10 ..12MB
  short* KVTb   = (short*)(base + (12u<<20));            // 12 ..16MB (4MB)
  float* KVT    = (float*)(base + (16u<<20));            // 16 ..24MB (8MB)
  short* WT     = (short*)(base + (24u<<20));            // 24MB.. +160KB
  float* Ksum   = (float*)(base + (24u<<20) + (256u<<10)); // +64KB

  short* WoT = WT + 4*D_*D_;

  k_prep<<<261, 256, 0, stream>>>(Wq, Wk, Wv, Wg, Wo, tokens, g1, b1, WT, xb);
  k_qkvg<<<dim3(NTOK/32, 3), 256, 0, stream>>>(xb, WT, bg, Qp, Kp, KpT, VgT);
  k_chunkkv<<<dim3(NCH, 2, 2), 256, 0, stream>>>(KpT, VgT, KVT, Ksum);
  k_prefix<<<129, 256, 0, stream>>>(KVT, KVTb, Ksum);
  k_attnout<<<dim3(NCH, 2), 256, 0, stream>>>(Qp, Kp, VgT, KVTb, Ksum, attn);
  k_outln2<<<NTOK/16, 256, 0, stream>>>(attn, WoT, tokens, g2, b2, (float*)d_out);
}